// Round 1
// baseline (466.751 us; speedup 1.0000x reference)
//
#include <hip/hip_runtime.h>
#include <stdint.h>

typedef unsigned short u16;
typedef __attribute__((ext_vector_type(8))) __bf16 bf16x8;
typedef __attribute__((ext_vector_type(4))) float f32x4;

// ---------- helpers ----------
__device__ __forceinline__ u16 f2bf(float f) {  // RNE fp32 -> bf16
  unsigned int u = __builtin_bit_cast(unsigned int, f);
  u = (u + 0x7FFFu + ((u >> 16) & 1u)) >> 16;
  return (u16)u;
}
__device__ __forceinline__ u16 tern2bf(int s) {
  return s == 0 ? (u16)0 : (s > 0 ? (u16)0x3F80 : (u16)0xBF80);
}

#define GLOAD_LDS16(g, l)                                                          \
  __builtin_amdgcn_global_load_lds((__attribute__((address_space(1))) void*)(g),   \
                                   (__attribute__((address_space(3))) void*)(l),   \
                                   16, 0, 0)

// ---------- problem sizes ----------
#define M_TOK 8192
#define N_OUT 4096
#define K_IN  4096
#define RANK  32

// ---------- ws layout (bytes) ----------
#define WS_XB    0ull                     // x bf16  [8192][4096]  = 67,108,864
#define WS_WB    67108864ull              // W bf16  [4096][4096]  = 33,554,432
#define WS_BB    100663296ull             // B bf16  [32][4096]    = 262,144
#define WS_APAD  100925440ull             // A' bf16 [4096][64]    = 524,288
#define WS_TPAD  101449728ull             // T bf16  [8192][64]    = 1,048,576
#define WS_TPART 102498304ull             // T part  [8][8192][32] f32 = 8,388,608
#define WS_FLAG  110886912ull             // int flag

// ---------- prep kernels ----------
__global__ void k_convert_x(const float4* __restrict__ x, ushort4* __restrict__ xb, int n4) {
  int stride = gridDim.x * blockDim.x;
  for (int i = blockIdx.x * blockDim.x + threadIdx.x; i < n4; i += stride) {
    float4 v = x[i];
    ushort4 o;
    o.x = f2bf(v.x); o.y = f2bf(v.y); o.z = f2bf(v.z); o.w = f2bf(v.w);
    xb[i] = o;
  }
}

// one wave: decide if weight buffer is int8 (raw) or int32 (widened)
__global__ void k_detect_wtype(const int* __restrict__ w, int* __restrict__ flag) {
  int v = w[threadIdx.x];
  bool ok = (v >= -1 && v <= 1);
  unsigned long long m = __ballot(ok);
  if (threadIdx.x == 0) *flag = (m == ~0ull) ? 1 : 0;
}

__global__ void k_convert_w(const void* __restrict__ wq, const int* __restrict__ flag,
                            ushort4* __restrict__ wb, int n4) {
  int is32 = *flag;
  int stride = gridDim.x * blockDim.x;
  for (int i = blockIdx.x * blockDim.x + threadIdx.x; i < n4; i += stride) {
    int s0, s1, s2, s3;
    if (is32) {
      int4 c = ((const int4*)wq)[i];
      s0 = c.x; s1 = c.y; s2 = c.z; s3 = c.w;
    } else {
      char4 c = ((const char4*)wq)[i];
      s0 = c.x; s1 = c.y; s2 = c.z; s3 = c.w;
    }
    ushort4 o;
    o.x = tern2bf(s0); o.y = tern2bf(s1); o.z = tern2bf(s2); o.w = tern2bf(s3);
    wb[i] = o;
  }
}

__global__ void k_prep_B(const float* __restrict__ loraB, u16* __restrict__ bb) {
  int idx = blockIdx.x * blockDim.x + threadIdx.x;  // 32*4096
  if (idx < RANK * K_IN) bb[idx] = f2bf(loraB[idx]);
}

__global__ void k_prep_A(const float* __restrict__ loraA, const float* __restrict__ scale,
                         u16* __restrict__ apad) {
  int idx = blockIdx.x * blockDim.x + threadIdx.x;  // 4096*64
  if (idx >= N_OUT * 64) return;
  int o = idx >> 6, r = idx & 63;
  float v = (r < RANK) ? (loraA[o * RANK + r] / scale[o]) : 0.f;
  apad[idx] = f2bf(v);
}

// ---------- T = x @ B^T (partials over 8 K-slices) ----------
__global__ __launch_bounds__(256) void k_lora_T(const u16* __restrict__ xb,
                                                const u16* __restrict__ bb,
                                                float* __restrict__ tpart) {
  __shared__ u16 As[256 * 32];  // 16 KB
  __shared__ u16 Bs[32 * 32];   //  2 KB
  int mt = blockIdx.x >> 3;     // 0..31
  int ks = blockIdx.x & 7;      // 0..7
  int tid = threadIdx.x, lane = tid & 63, wave = tid >> 6;
  int m0 = mt * 256;
  int kbase0 = ks * 512;
  f32x4 acc[4][2] = {};
  for (int step = 0; step < 16; ++step) {
    int kb = kbase0 + step * 32;
    __syncthreads();
#pragma unroll
    for (int i = 0; i < 4; ++i) {
      const u16* src = xb + (size_t)(m0 + i * 64 + (tid >> 2)) * K_IN + kb + (tid & 3) * 8;
      GLOAD_LDS16(src, &As[i * 2048 + tid * 8]);
    }
    if (tid < 128) {
      const u16* src = bb + (size_t)(tid >> 2) * K_IN + kb + (tid & 3) * 8;
      GLOAD_LDS16(src, &Bs[tid * 8]);
    }
    __syncthreads();
    bf16x8 b[2];
#pragma unroll
    for (int ni = 0; ni < 2; ++ni)
      b[ni] = *(const bf16x8*)&Bs[(ni * 16 + (lane & 15)) * 32 + (lane >> 4) * 8];
#pragma unroll
    for (int mi = 0; mi < 4; ++mi) {
      bf16x8 a = *(const bf16x8*)&As[(wave * 64 + mi * 16 + (lane & 15)) * 32 + (lane >> 4) * 8];
      acc[mi][0] = __builtin_amdgcn_mfma_f32_16x16x32_bf16(a, b[0], acc[mi][0], 0, 0, 0);
      acc[mi][1] = __builtin_amdgcn_mfma_f32_16x16x32_bf16(a, b[1], acc[mi][1], 0, 0, 0);
    }
  }
#pragma unroll
  for (int mi = 0; mi < 4; ++mi)
#pragma unroll
    for (int ni = 0; ni < 2; ++ni)
#pragma unroll
      for (int r = 0; r < 4; ++r) {
        int row = m0 + wave * 64 + mi * 16 + (lane >> 4) * 4 + r;
        int col = ni * 16 + (lane & 15);
        tpart[((size_t)ks * M_TOK + row) * RANK + col] = acc[mi][ni][r];
      }
}

__global__ void k_reduce_T(const float* __restrict__ tpart, u16* __restrict__ tpad) {
  int idx = blockIdx.x * blockDim.x + threadIdx.x;  // 8192*64
  if (idx >= M_TOK * 64) return;
  int t = idx >> 6, r = idx & 63;
  float v = 0.f;
  if (r < RANK) {
#pragma unroll
    for (int s = 0; s < 8; ++s) v += tpart[((size_t)s * M_TOK + t) * RANK + r];
  }
  tpad[idx] = f2bf(v);
}

// ---------- main GEMM: C = (x@Wq^T + T@A'^T)*scale + bias ----------
// 128x128 tile, BK=64, K-extension step 64 = LoRA
__global__ __launch_bounds__(256) void k_gemm(const u16* __restrict__ xb,
                                              const u16* __restrict__ wb,
                                              const u16* __restrict__ tpad,
                                              const u16* __restrict__ apad,
                                              const float* __restrict__ scale,
                                              const float* __restrict__ bias,
                                              float* __restrict__ out) {
  __shared__ u16 As[128 * 64];  // 16 KB
  __shared__ u16 Bs[128 * 64];  // 16 KB
  int bid = blockIdx.x;
  int swz = (bid & 7) * 256 + (bid >> 3);  // 2048 = 8*256, bijective XCD swizzle
  int bm = swz >> 5, bn = swz & 31;        // 64 x 32 tiles
  int m0 = bm * 128, n0 = bn * 128;
  int tid = threadIdx.x, lane = tid & 63, wave = tid >> 6;
  int wr = wave >> 1, wc = wave & 1;
  int srow = tid >> 3;          // staging row 0..31 (+32 per issue)
  int scol = (tid & 7) * 8;     // staging col (bf16 units)
  f32x4 acc[4][4] = {};

  for (int step = 0; step < 65; ++step) {
    __syncthreads();
    if (step < 64) {
      int kb = step * 64;
      const u16* ax = xb + (size_t)(m0 + srow) * K_IN + kb + scol;
      const u16* bx = wb + (size_t)(n0 + srow) * K_IN + kb + scol;
#pragma unroll
      for (int i = 0; i < 4; ++i) GLOAD_LDS16(ax + (size_t)i * 32 * K_IN, &As[i * 2048 + tid * 8]);
#pragma unroll
      for (int i = 0; i < 4; ++i) GLOAD_LDS16(bx + (size_t)i * 32 * K_IN, &Bs[i * 2048 + tid * 8]);
    } else {  // LoRA K-extension: A-side = T_pad, B-side = A'_pad (both [.][64])
      const u16* ax = tpad + (size_t)(m0 + srow) * 64 + scol;
      const u16* bx = apad + (size_t)(n0 + srow) * 64 + scol;
#pragma unroll
      for (int i = 0; i < 4; ++i) GLOAD_LDS16(ax + (size_t)i * 32 * 64, &As[i * 2048 + tid * 8]);
#pragma unroll
      for (int i = 0; i < 4; ++i) GLOAD_LDS16(bx + (size_t)i * 32 * 64, &Bs[i * 2048 + tid * 8]);
    }
    __syncthreads();
#pragma unroll
    for (int ksub = 0; ksub < 2; ++ksub) {
      int ko = ksub * 32 + (lane >> 4) * 8;
      bf16x8 a[4], b[4];
#pragma unroll
      for (int mi = 0; mi < 4; ++mi)
        a[mi] = *(const bf16x8*)&As[(wr * 64 + mi * 16 + (lane & 15)) * 64 + ko];
#pragma unroll
      for (int ni = 0; ni < 4; ++ni)
        b[ni] = *(const bf16x8*)&Bs[(wc * 64 + ni * 16 + (lane & 15)) * 64 + ko];
#pragma unroll
      for (int mi = 0; mi < 4; ++mi)
#pragma unroll
        for (int ni = 0; ni < 4; ++ni)
          acc[mi][ni] = __builtin_amdgcn_mfma_f32_16x16x32_bf16(a[mi], b[ni], acc[mi][ni], 0, 0, 0);
    }
  }
  // epilogue: *scale + bias  (C/D: col=lane&15, row=(lane>>4)*4+reg)
#pragma unroll
  for (int ni = 0; ni < 4; ++ni) {
    int col = n0 + wc * 64 + ni * 16 + (lane & 15);
    float s = scale[col], bsv = bias[col];
#pragma unroll
    for (int mi = 0; mi < 4; ++mi) {
      int row = m0 + wr * 64 + mi * 16 + (lane >> 4) * 4;
#pragma unroll
      for (int r = 0; r < 4; ++r)
        out[(size_t)(row + r) * N_OUT + col] = acc[mi][ni][r] * s + bsv;
    }
  }
}

// ---------- launch ----------
extern "C" void kernel_launch(void* const* d_in, const int* in_sizes, int n_in,
                              void* d_out, int out_size, void* d_ws, size_t ws_size,
                              hipStream_t stream) {
  const float* x     = (const float*)d_in[0];
  const void*  wq    = d_in[1];
  const float* scale = (const float*)d_in[2];
  const float* loraA = (const float*)d_in[3];
  const float* loraB = (const float*)d_in[4];
  const float* bias  = (const float*)d_in[5];
  float* out = (float*)d_out;

  char* ws = (char*)d_ws;
  u16*   xb    = (u16*)(ws + WS_XB);
  u16*   wbuf  = (u16*)(ws + WS_WB);
  u16*   bb    = (u16*)(ws + WS_BB);
  u16*   apad  = (u16*)(ws + WS_APAD);
  u16*   tpad  = (u16*)(ws + WS_TPAD);
  float* tpart = (float*)(ws + WS_TPART);
  int*   flag  = (int*)(ws + WS_FLAG);

  // 1. x -> bf16
  k_convert_x<<<2048, 256, 0, stream>>>((const float4*)x, (ushort4*)xb, M_TOK * K_IN / 4);
  // 2. weight dtype detect + convert
  k_detect_wtype<<<1, 64, 0, stream>>>((const int*)wq, flag);
  k_convert_w<<<2048, 256, 0, stream>>>(wq, flag, (ushort4*)wbuf, N_OUT * K_IN / 4);
  // 3. small preps
  k_prep_B<<<512, 256, 0, stream>>>(loraB, bb);
  k_prep_A<<<1024, 256, 0, stream>>>(loraA, scale, apad);
  // 4. T = x@B^T partials, then reduce+pad to bf16
  k_lora_T<<<256, 256, 0, stream>>>(xb, bb, tpart);
  k_reduce_T<<<2048, 256, 0, stream>>>(tpart, tpad);
  // 5. fused main GEMM
  k_gemm<<<2048, 256, 0, stream>>>(xb, wbuf, tpad, apad, scale, bias, out);

  (void)in_sizes; (void)n_in; (void)out_size; (void)ws_size;
}

// Round 2
// 340.339 us; speedup vs baseline: 1.3714x; 1.3714x over previous
//
#include <hip/hip_runtime.h>
#include <stdint.h>

typedef unsigned short u16;
typedef __attribute__((ext_vector_type(8))) __bf16 bf16x8;
typedef __attribute__((ext_vector_type(4))) float f32x4;

// ---------- helpers ----------
__device__ __forceinline__ u16 f2bf(float f) {  // RNE fp32 -> bf16
  unsigned int u = __builtin_bit_cast(unsigned int, f);
  u = (u + 0x7FFFu + ((u >> 16) & 1u)) >> 16;
  return (u16)u;
}
__device__ __forceinline__ u16 tern2bf(int s) {
  return s == 0 ? (u16)0 : (s > 0 ? (u16)0x3F80 : (u16)0xBF80);
}

#define GLOAD_LDS16(g, l)                                                          \
  __builtin_amdgcn_global_load_lds((__attribute__((address_space(1))) void*)(g),   \
                                   (__attribute__((address_space(3))) void*)(l),   \
                                   16, 0, 0)

// ---------- problem sizes ----------
#define M_TOK 8192
#define N_OUT 4096
#define K_IN  4096
#define RANK  32

// ---------- ws layout (bytes) ----------
#define WS_XB    0ull                     // x bf16  [8192][4096]  = 67,108,864
#define WS_WB    67108864ull              // W bf16  [4096][4096]  = 33,554,432
#define WS_BB    100663296ull             // B bf16  [32][4096]    = 262,144
#define WS_A32   100925440ull             // A' bf16 [4096][32]    = 262,144
#define WS_T32   101187584ull             // T bf16  [8192][32]    = 524,288
#define WS_TPART 101711872ull             // T part  [8][8192][32] f32 = 8,388,608
#define WS_FLAG  110100480ull             // int flag

// ---------- prep kernels ----------
__global__ void k_convert_x(const float4* __restrict__ x, ushort4* __restrict__ xb, int n4) {
  int stride = gridDim.x * blockDim.x;
  for (int i = blockIdx.x * blockDim.x + threadIdx.x; i < n4; i += stride) {
    float4 v = x[i];
    ushort4 o;
    o.x = f2bf(v.x); o.y = f2bf(v.y); o.z = f2bf(v.z); o.w = f2bf(v.w);
    xb[i] = o;
  }
}

__global__ void k_detect_wtype(const int* __restrict__ w, int* __restrict__ flag) {
  int v = w[threadIdx.x];
  bool ok = (v >= -1 && v <= 1);
  unsigned long long m = __ballot(ok);
  if (threadIdx.x == 0) *flag = (m == ~0ull) ? 1 : 0;
}

__global__ void k_convert_w(const void* __restrict__ wq, const int* __restrict__ flag,
                            ushort4* __restrict__ wb, int n4) {
  int is32 = *flag;
  int stride = gridDim.x * blockDim.x;
  for (int i = blockIdx.x * blockDim.x + threadIdx.x; i < n4; i += stride) {
    int s0, s1, s2, s3;
    if (is32) {
      int4 c = ((const int4*)wq)[i];
      s0 = c.x; s1 = c.y; s2 = c.z; s3 = c.w;
    } else {
      char4 c = ((const char4*)wq)[i];
      s0 = c.x; s1 = c.y; s2 = c.z; s3 = c.w;
    }
    ushort4 o;
    o.x = tern2bf(s0); o.y = tern2bf(s1); o.z = tern2bf(s2); o.w = tern2bf(s3);
    wb[i] = o;
  }
}

__global__ void k_prep_B(const float* __restrict__ loraB, u16* __restrict__ bb) {
  int idx = blockIdx.x * blockDim.x + threadIdx.x;  // 32*4096
  if (idx < RANK * K_IN) bb[idx] = f2bf(loraB[idx]);
}

__global__ void k_prep_A(const float* __restrict__ loraA, const float* __restrict__ scale,
                         u16* __restrict__ a32) {
  int idx = blockIdx.x * blockDim.x + threadIdx.x;  // 4096*32
  if (idx >= N_OUT * RANK) return;
  int o = idx >> 5;
  a32[idx] = f2bf(loraA[idx] / scale[o]);
}

// ---------- T = x @ B^T (partials over 8 K-slices) ----------
__global__ __launch_bounds__(256) void k_lora_T(const u16* __restrict__ xb,
                                                const u16* __restrict__ bb,
                                                float* __restrict__ tpart) {
  __shared__ u16 As[256 * 32];
  __shared__ u16 Bs[32 * 32];
  int mt = blockIdx.x >> 3;
  int ks = blockIdx.x & 7;
  int tid = threadIdx.x, lane = tid & 63, wave = tid >> 6;
  int m0 = mt * 256;
  int kbase0 = ks * 512;
  f32x4 acc[4][2] = {};
  for (int step = 0; step < 16; ++step) {
    int kb = kbase0 + step * 32;
    __syncthreads();
#pragma unroll
    for (int i = 0; i < 4; ++i) {
      const u16* src = xb + (size_t)(m0 + i * 64 + (tid >> 2)) * K_IN + kb + (tid & 3) * 8;
      GLOAD_LDS16(src, &As[i * 2048 + tid * 8]);
    }
    if (tid < 128) {
      const u16* src = bb + (size_t)(tid >> 2) * K_IN + kb + (tid & 3) * 8;
      GLOAD_LDS16(src, &Bs[tid * 8]);
    }
    __syncthreads();
    bf16x8 b[2];
#pragma unroll
    for (int ni = 0; ni < 2; ++ni)
      b[ni] = *(const bf16x8*)&Bs[(ni * 16 + (lane & 15)) * 32 + (lane >> 4) * 8];
#pragma unroll
    for (int mi = 0; mi < 4; ++mi) {
      bf16x8 a = *(const bf16x8*)&As[(wave * 64 + mi * 16 + (lane & 15)) * 32 + (lane >> 4) * 8];
      acc[mi][0] = __builtin_amdgcn_mfma_f32_16x16x32_bf16(a, b[0], acc[mi][0], 0, 0, 0);
      acc[mi][1] = __builtin_amdgcn_mfma_f32_16x16x32_bf16(a, b[1], acc[mi][1], 0, 0, 0);
    }
  }
#pragma unroll
  for (int mi = 0; mi < 4; ++mi)
#pragma unroll
    for (int ni = 0; ni < 2; ++ni)
#pragma unroll
      for (int r = 0; r < 4; ++r) {
        int row = m0 + wave * 64 + mi * 16 + (lane >> 4) * 4 + r;
        int col = ni * 16 + (lane & 15);
        tpart[((size_t)ks * M_TOK + row) * RANK + col] = acc[mi][ni][r];
      }
}

__global__ void k_reduce_T(const float* __restrict__ tpart, u16* __restrict__ t32) {
  int idx = blockIdx.x * blockDim.x + threadIdx.x;  // 8192*32
  if (idx >= M_TOK * RANK) return;
  int t = idx >> 5, r = idx & 31;
  float v = 0.f;
#pragma unroll
  for (int s = 0; s < 8; ++s) v += tpart[((size_t)s * M_TOK + t) * RANK + r];
  t32[idx] = f2bf(v);
}

// ---------- main GEMM: 256x256 tile, BK=32, ring-4 LDS pipeline ----------
// 8 waves (2M x 4N), per-wave out 128x64 = acc[8][4] frags.
// LDS swizzle: logical (row, chunk c of 8 bf16) stored at chunk c ^ ((row>>1)&3).
// Stage via global_load_lds (linear dest) with pre-swizzled SOURCE address.
// Pipeline: stage tile t+3 while computing tile t; vmcnt(8) once per tile
// guarantees tile t+1 landed (newest 8 outstanding = tiles t+2,t+3 stages).
__global__ __launch_bounds__(512, 2) void k_gemm8(const u16* __restrict__ xb,
                                                  const u16* __restrict__ wb,
                                                  const u16* __restrict__ t32,
                                                  const u16* __restrict__ a32,
                                                  const float* __restrict__ scale,
                                                  const float* __restrict__ bias,
                                                  float* __restrict__ out) {
  __shared__ u16 As[4][8192];  // 4 slots x 16KB
  __shared__ u16 Bs[4][8192];
  const int tid = threadIdx.x;
  const int l = tid & 63, w = tid >> 6;
  const int wm = w >> 2, wn = w & 3;
  const int bid = blockIdx.x;                    // 512 blocks, 512%8==0
  const int swz = (bid & 7) * 64 + (bid >> 3);   // bijective XCD swizzle
  const int m0 = (swz >> 4) * 256, n0 = (swz & 15) * 256;

  // staging map: load j of wave w covers LDS bytes [(w*2+j)*1024 + lane*16)
  const int srow0 = (w * 2 + 0) * 16 + (l >> 2);
  const int srow1 = (w * 2 + 1) * 16 + (l >> 2);
  const int scx = ((l & 3) ^ ((l >> 3) & 3)) * 8;  // pre-swizzled source chunk (u16)
  const int ldst0 = (w * 2 + 0) * 512 + l * 8;     // u16 index
  const int ldst1 = (w * 2 + 1) * 512 + l * 8;
  // frag-read map
  const int r15 = l & 15;
  const int cxr = (((l >> 4) ^ ((r15 >> 1) & 3)) * 8);  // swizzled chunk (u16)

  f32x4 acc[8][4] = {};

  auto stageA = [&](int ts) {
    int tc = ts < 128 ? ts : 128;
    const u16 *s0, *s1;
    if (tc < 128) {
      s0 = xb + (size_t)(m0 + srow0) * K_IN + tc * 32 + scx;
      s1 = xb + (size_t)(m0 + srow1) * K_IN + tc * 32 + scx;
    } else {
      s0 = t32 + (size_t)(m0 + srow0) * RANK + scx;
      s1 = t32 + (size_t)(m0 + srow1) * RANK + scx;
    }
    u16* d = &As[ts & 3][0];
    GLOAD_LDS16(s0, d + ldst0);
    GLOAD_LDS16(s1, d + ldst1);
  };
  auto stageB = [&](int ts) {
    int tc = ts < 128 ? ts : 128;
    const u16 *s0, *s1;
    if (tc < 128) {
      s0 = wb + (size_t)(n0 + srow0) * K_IN + tc * 32 + scx;
      s1 = wb + (size_t)(n0 + srow1) * K_IN + tc * 32 + scx;
    } else {
      s0 = a32 + (size_t)(n0 + srow0) * RANK + scx;
      s1 = a32 + (size_t)(n0 + srow1) * RANK + scx;
    }
    u16* d = &Bs[ts & 3][0];
    GLOAD_LDS16(s0, d + ldst0);
    GLOAD_LDS16(s1, d + ldst1);
  };

  // prologue: stage tiles 0,1,2 (12 loads/wave); wait until tile 0 landed
  stageA(0); stageB(0);
  stageA(1); stageB(1);
  stageA(2); stageB(2);
  asm volatile("s_waitcnt vmcnt(8)" ::: "memory");
  __builtin_amdgcn_s_barrier();

#pragma unroll 1
  for (int t = 0; t < 129; ++t) {
    const u16* Asl = &As[t & 3][0];
    const u16* Bsl = &Bs[t & 3][0];
    // ---- phase 0: quadrant rows [0,64) of wave's 128; read B once for both phases
    bf16x8 af0[4], bfr[4];
    {
      const int ab = (wm * 128 + r15) * 32 + cxr;
#pragma unroll
      for (int mi = 0; mi < 4; ++mi) af0[mi] = *(const bf16x8*)&Asl[ab + mi * 512];
      const int bb2 = (wn * 64 + r15) * 32 + cxr;
#pragma unroll
      for (int nj = 0; nj < 4; ++nj) bfr[nj] = *(const bf16x8*)&Bsl[bb2 + nj * 512];
    }
    stageA(t + 3);
    __builtin_amdgcn_s_barrier();
    asm volatile("s_waitcnt lgkmcnt(0)" ::: "memory");
    __builtin_amdgcn_s_setprio(1);
#pragma unroll
    for (int mi = 0; mi < 4; ++mi)
#pragma unroll
      for (int nj = 0; nj < 4; ++nj)
        acc[mi][nj] = __builtin_amdgcn_mfma_f32_16x16x32_bf16(af0[mi], bfr[nj], acc[mi][nj], 0, 0, 0);
    __builtin_amdgcn_s_setprio(0);
    __builtin_amdgcn_s_barrier();
    // ---- phase 1: quadrant rows [64,128)
    bf16x8 af1[4];
    {
      const int ab = (wm * 128 + 64 + r15) * 32 + cxr;
#pragma unroll
      for (int mi = 0; mi < 4; ++mi) af1[mi] = *(const bf16x8*)&Asl[ab + mi * 512];
    }
    stageB(t + 3);
    asm volatile("s_waitcnt vmcnt(8)" ::: "memory");  // tile t+1 fully landed
    __builtin_amdgcn_s_barrier();
    asm volatile("s_waitcnt lgkmcnt(0)" ::: "memory");
    __builtin_amdgcn_s_setprio(1);
#pragma unroll
    for (int mi = 0; mi < 4; ++mi)
#pragma unroll
      for (int nj = 0; nj < 4; ++nj)
        acc[4 + mi][nj] = __builtin_amdgcn_mfma_f32_16x16x32_bf16(af1[mi], bfr[nj], acc[4 + mi][nj], 0, 0, 0);
    __builtin_amdgcn_s_setprio(0);
    __builtin_amdgcn_s_barrier();
  }

  // epilogue: out = acc*scale[col] + bias[col]
#pragma unroll
  for (int nj = 0; nj < 4; ++nj) {
    int col = n0 + wn * 64 + nj * 16 + r15;
    float s = scale[col], bv = bias[col];
#pragma unroll
    for (int fi = 0; fi < 8; ++fi) {
      int row = m0 + wm * 128 + (fi >> 2) * 64 + (fi & 3) * 16 + (l >> 4) * 4;
#pragma unroll
      for (int r = 0; r < 4; ++r)
        out[(size_t)(row + r) * N_OUT + col] = acc[fi][nj][r] * s + bv;
    }
  }
}

// ---------- launch ----------
extern "C" void kernel_launch(void* const* d_in, const int* in_sizes, int n_in,
                              void* d_out, int out_size, void* d_ws, size_t ws_size,
                              hipStream_t stream) {
  const float* x     = (const float*)d_in[0];
  const void*  wq    = d_in[1];
  const float* scale = (const float*)d_in[2];
  const float* loraA = (const float*)d_in[3];
  const float* loraB = (const float*)d_in[4];
  const float* bias  = (const float*)d_in[5];
  float* out = (float*)d_out;

  char* ws = (char*)d_ws;
  u16*   xb    = (u16*)(ws + WS_XB);
  u16*   wbuf  = (u16*)(ws + WS_WB);
  u16*   bb    = (u16*)(ws + WS_BB);
  u16*   a32   = (u16*)(ws + WS_A32);
  u16*   t32   = (u16*)(ws + WS_T32);
  float* tpart = (float*)(ws + WS_TPART);
  int*   flag  = (int*)(ws + WS_FLAG);

  k_convert_x<<<2048, 256, 0, stream>>>((const float4*)x, (ushort4*)xb, M_TOK * K_IN / 4);
  k_detect_wtype<<<1, 64, 0, stream>>>((const int*)wq, flag);
  k_convert_w<<<2048, 256, 0, stream>>>(wq, flag, (ushort4*)wbuf, N_OUT * K_IN / 4);
  k_prep_B<<<512, 256, 0, stream>>>(loraB, bb);
  k_prep_A<<<512, 256, 0, stream>>>(loraA, scale, a32);
  k_lora_T<<<256, 256, 0, stream>>>(xb, bb, tpart);
  k_reduce_T<<<1024, 256, 0, stream>>>(tpart, t32);
  k_gemm8<<<512, 512, 0, stream>>>(xb, wbuf, t32, a32, scale, bias, out);

  (void)in_sizes; (void)n_in; (void)out_size; (void)ws_size;
}